// Round 2
// baseline (342.241 us; speedup 1.0000x reference)
//
#include <hip/hip_runtime.h>

// Problem constants (from reference)
#define BATCH 16
#define HL 128
#define WL 128
#define HH 1024
#define WH 1024
#define CH 3
#define NP 16      // N_PATCHES
#define PH 128     // PATCH_H
#define PW 128     // PATCH_W

#define TOTAL4 (BATCH * NP * PH * PW * CH / 4)   // 3,145,728 float4 in patches
#define F4_PER_THREAD 8

// ---------------------------------------------------------------------------
// Kernel 1: per-batch Gumbel top-k (k=16) over 16384 scores.
// One block (256 threads) per batch. Each thread holds 64 scores in registers.
// 16 iterative argmax rounds -> indices in descending-score order, matching
// jax.lax.top_k (ties broken toward smaller index).
// Writes sampled_attention directly to d_out tail, and top/left coords to ws.
// ---------------------------------------------------------------------------
__global__ __launch_bounds__(256) void topk_kernel(
    const float* __restrict__ att,    // [BATCH, HL*WL]
    const float* __restrict__ gum,    // [BATCH, HL*WL]
    float* __restrict__ out_att,      // [BATCH, NP]
    int* __restrict__ tops,           // [BATCH*NP]
    int* __restrict__ lefts)          // [BATCH*NP]
{
    const int b   = blockIdx.x;
    const int tid = threadIdx.x;
    const float* a = att + (size_t)b * (HL * WL);
    const float* g = gum + (size_t)b * (HL * WL);

    // Load 64 scores per thread (coalesced: element e = tid + t*256)
    float sc[64];
#pragma unroll
    for (int t = 0; t < 64; ++t) {
        const int e = tid + t * 256;
        sc[t] = logf(a[e]) + g[e];
    }

    __shared__ float s_val[4];
    __shared__ int   s_idx[4];
    __shared__ int   s_win;

    unsigned long long taken = 0ULL;
    const int lane = tid & 63;
    const int wave = tid >> 6;

    for (int r = 0; r < NP; ++r) {
        // local argmax over untaken elements (tie -> smaller global index)
        float best = -3.0e38f;
        int   bidx = 0x7fffffff;
#pragma unroll
        for (int t = 0; t < 64; ++t) {
            if (!((taken >> t) & 1ULL)) {
                const float v = sc[t];
                const int   e = tid + t * 256;
                if (v > best || (v == best && e < bidx)) { best = v; bidx = e; }
            }
        }
        // wave (64-lane) argmax butterfly reduce
#pragma unroll
        for (int off = 32; off; off >>= 1) {
            const float ov = __shfl_down(best, off);
            const int   oi = __shfl_down(bidx, off);
            if (ov > best || (ov == best && oi < bidx)) { best = ov; bidx = oi; }
        }
        if (lane == 0) { s_val[wave] = best; s_idx[wave] = bidx; }
        __syncthreads();
        if (tid == 0) {
            float bv = s_val[0];
            int   bi = s_idx[0];
#pragma unroll
            for (int w = 1; w < 4; ++w) {
                if (s_val[w] > bv || (s_val[w] == bv && s_idx[w] < bi)) {
                    bv = s_val[w]; bi = s_idx[w];
                }
            }
            s_win = bi;
            // emit outputs for this rank
            const int si = bi / WL;
            const int sj = bi % WL;
            int t_ = si * 8; if (t_ > HH - PH) t_ = HH - PH;   // clip to 896
            int l_ = sj * 8; if (l_ > WH - PW) l_ = WH - PW;   // clip to 896
            tops[b * NP + r]  = t_;
            lefts[b * NP + r] = l_;
            out_att[b * NP + r] = a[bi];
        }
        __syncthreads();
        const int win = s_win;
        if ((win & 255) == tid) taken |= 1ULL << (win >> 8);
    }
}

// ---------------------------------------------------------------------------
// Kernel 2: gather patches. Each thread copies 8 float4 (128 B), strided by
// 256 float4 within its block's 2048-float4 chunk -> every access step is a
// fully-coalesced 16 B/lane wave access. tops/lefts (2 KB) stay L1-resident.
// ---------------------------------------------------------------------------
__global__ __launch_bounds__(256) void gather_kernel(
    const float* __restrict__ xh,     // [BATCH, HH, WH, CH]
    const int* __restrict__ tops,
    const int* __restrict__ lefts,
    float* __restrict__ out)          // [BATCH, NP, PH, PW, CH]
{
    const int base = blockIdx.x * (256 * F4_PER_THREAD) + threadIdx.x;
#pragma unroll
    for (int s = 0; s < F4_PER_THREAD; ++s) {
        const int j4 = base + s * 256;           // < TOTAL4
        const int lane = j4 % 96;                // float4 within patch row
        const int row  = j4 / 96;                // global patch-row id
        const int b    = row >> 11;              // 2048 patch-rows per batch
        const int rem  = row & 2047;
        const int n    = rem >> 7;
        const int ph   = rem & 127;
        const int tl   = (b << 4) + n;
        const int top  = tops[tl];
        const int left = lefts[tl];
        const size_t src4 = (size_t)(b * HH + top + ph) * (WH * CH / 4)
                          + ((left * CH) >> 2) + lane;
        ((float4*)out)[j4] = ((const float4*)xh)[src4];
    }
}

extern "C" void kernel_launch(void* const* d_in, const int* in_sizes, int n_in,
                              void* d_out, int out_size, void* d_ws, size_t ws_size,
                              hipStream_t stream) {
    // inputs: 0=x_low (unused), 1=x_high, 2=attention, 3=gumbel_noise
    const float* xh  = (const float*)d_in[1];
    const float* att = (const float*)d_in[2];
    const float* gum = (const float*)d_in[3];

    float* out_patches = (float*)d_out;                       // 12,582,912 floats
    float* out_att     = (float*)d_out + (size_t)BATCH * NP * PH * PW * CH;

    int* tops  = (int*)d_ws;
    int* lefts = (int*)d_ws + BATCH * NP;

    topk_kernel<<<BATCH, 256, 0, stream>>>(att, gum, out_att, tops, lefts);

    gather_kernel<<<TOTAL4 / (256 * F4_PER_THREAD), 256, 0, stream>>>(
        xh, tops, lefts, out_patches);
}

// Round 10
// 292.864 us; speedup vs baseline: 1.1686x; 1.1686x over previous
//
#include <hip/hip_runtime.h>

// Problem constants (from reference)
#define BATCH 16
#define HL 128
#define WL 128
#define HH 1024
#define WH 1024
#define CH 3
#define NP 16      // N_PATCHES
#define PH 128     // PATCH_H
#define PW 128     // PATCH_W

#define NEL (HL * WL)                            // 16384 scores per batch
#define TOTAL4 (BATCH * NP * PH * PW * CH / 4)   // 3,145,728 float4 in patches
#define F4_PER_THREAD 16

typedef float f32x4 __attribute__((ext_vector_type(4)));  // clang vector: OK for
                                                          // __builtin_nontemporal_*

// ---------------------------------------------------------------------------
// Kernel 1: per-batch Gumbel top-k (k=16) over 16384 scores.
// 1024 threads/block (one block per batch), 16 scores/thread in registers.
// 16 iterative argmax rounds; after each round only the thread that owned the
// winner rescans its (16-deep) local chain — all other threads' cached local
// argmax is unchanged. Two-stage reduce: 64-lane shfl per wave -> 16 wave
// leaders -> 16-lane shfl butterfly in wave 0. Ties break toward smaller
// index to match jax.lax.top_k; output emitted in descending-score order.
// ---------------------------------------------------------------------------
__global__ __launch_bounds__(1024) void topk_kernel(
    const float* __restrict__ att,    // [BATCH, NEL]
    const float* __restrict__ gum,    // [BATCH, NEL]
    float* __restrict__ out_att,      // [BATCH, NP]
    int* __restrict__ tops,           // [BATCH*NP]
    int* __restrict__ lefts)          // [BATCH*NP]
{
    const int b   = blockIdx.x;
    const int tid = threadIdx.x;
    const float* a = att + (size_t)b * NEL;
    const float* g = gum + (size_t)b * NEL;

    // 16 scores per thread (coalesced: element e = tid + t*1024)
    float sc[16];
#pragma unroll
    for (int t = 0; t < 16; ++t) {
        const int e = tid + t * 1024;
        sc[t] = logf(a[e]) + g[e];
    }

    unsigned taken = 0;
    float best; int bidx;
    auto rescan = [&]() {
        best = -3.0e38f; bidx = 0x7fffffff;
#pragma unroll
        for (int t = 0; t < 16; ++t) {
            if (!((taken >> t) & 1u)) {
                const float v = sc[t];
                const int   e = tid + t * 1024;
                if (v > best || (v == best && e < bidx)) { best = v; bidx = e; }
            }
        }
    };
    rescan();

    __shared__ float s_val[16];
    __shared__ int   s_idx[16];
    __shared__ int   s_win;
    const int lane = tid & 63;
    const int wave = tid >> 6;

    for (int r = 0; r < NP; ++r) {
        // stage 1: 64-lane wave argmax
        float wb = best; int wi = bidx;
#pragma unroll
        for (int off = 32; off; off >>= 1) {
            const float ov = __shfl_down(wb, off);
            const int   oi = __shfl_down(wi, off);
            if (ov > wb || (ov == wb && oi < wi)) { wb = ov; wi = oi; }
        }
        if (lane == 0) { s_val[wave] = wb; s_idx[wave] = wi; }
        __syncthreads();
        // stage 2: 16 wave-leader values reduced by wave 0, lanes 0..15
        if (wave == 0 && lane < 16) {
            float v = s_val[lane]; int i = s_idx[lane];
#pragma unroll
            for (int off = 8; off; off >>= 1) {
                const float ov = __shfl_xor(v, off, 16);
                const int   oi = __shfl_xor(i, off, 16);
                if (ov > v || (ov == v && oi < i)) { v = ov; i = oi; }
            }
            if (lane == 0) {
                s_win = i;
                const int si = i >> 7;        // / WL
                const int sj = i & 127;       // % WL
                int t_ = si * 8; if (t_ > HH - PH) t_ = HH - PH;   // clip to 896
                int l_ = sj * 8; if (l_ > WH - PW) l_ = WH - PW;   // clip to 896
                tops[b * NP + r]  = t_;
                lefts[b * NP + r] = l_;
                out_att[b * NP + r] = a[i];
            }
        }
        __syncthreads();
        const int win = s_win;
        if ((win & 1023) == tid) {            // I owned the winner: remove + rescan
            taken |= 1u << (win >> 10);
            rescan();
        }
    }
}

// ---------------------------------------------------------------------------
// Kernel 2: gather patches. Each thread copies 16 float4 (256 B), strided by
// 256 float4 within its block's 4096-float4 chunk -> every access step is a
// fully-coalesced 16 B/lane wave access. Patch rows are 1536 B contiguous in
// both src and dst (left is a multiple of 8 -> 96 B-aligned float offset).
// Nontemporal load+store: both sides are streamed once, keep them out of L2.
// ---------------------------------------------------------------------------
__global__ __launch_bounds__(256) void gather_kernel(
    const float* __restrict__ xh,     // [BATCH, HH, WH, CH]
    const int* __restrict__ tops,
    const int* __restrict__ lefts,
    float* __restrict__ out)          // [BATCH, NP, PH, PW, CH]
{
    const int base = blockIdx.x * (256 * F4_PER_THREAD) + threadIdx.x;
#pragma unroll
    for (int s = 0; s < F4_PER_THREAD; ++s) {
        const int j4 = base + s * 256;           // < TOTAL4
        const int lane = j4 % 96;                // float4 within patch row
        const int row  = j4 / 96;                // global patch-row id
        const int b    = row >> 11;              // 2048 patch-rows per batch
        const int rem  = row & 2047;
        const int n    = rem >> 7;
        const int ph   = rem & 127;
        const int tl   = (b << 4) + n;
        const int top  = tops[tl];
        const int left = lefts[tl];
        const size_t src4 = (size_t)(b * HH + top + ph) * (WH * CH / 4)
                          + ((left * CH) >> 2) + lane;
        const f32x4 v = __builtin_nontemporal_load(((const f32x4*)xh) + src4);
        __builtin_nontemporal_store(v, ((f32x4*)out) + j4);
    }
}

extern "C" void kernel_launch(void* const* d_in, const int* in_sizes, int n_in,
                              void* d_out, int out_size, void* d_ws, size_t ws_size,
                              hipStream_t stream) {
    // inputs: 0=x_low (unused), 1=x_high, 2=attention, 3=gumbel_noise
    const float* xh  = (const float*)d_in[1];
    const float* att = (const float*)d_in[2];
    const float* gum = (const float*)d_in[3];

    float* out_patches = (float*)d_out;                       // 12,582,912 floats
    float* out_att     = (float*)d_out + (size_t)BATCH * NP * PH * PW * CH;

    int* tops  = (int*)d_ws;
    int* lefts = (int*)d_ws + BATCH * NP;

    topk_kernel<<<BATCH, 1024, 0, stream>>>(att, gum, out_att, tops, lefts);

    gather_kernel<<<TOTAL4 / (256 * F4_PER_THREAD), 256, 0, stream>>>(
        xh, tops, lefts, out_patches);
}